// Round 17
// baseline (3282.751 us; speedup 1.0000x reference)
//
#include <hip/hip_runtime.h>
#include <stdint.h>

#define NBATCH 128
#define NT     64
#define OBD    32
#define ACD    8
#define LDIM   128
#define HDIM   256

typedef _Float16 h2 __attribute__((ext_vector_type(2)));
typedef float    f4 __attribute__((ext_vector_type(4)));

#if defined(__has_builtin)
#  if __has_builtin(__builtin_amdgcn_fdot2)
#    define HAVE_FDOT2 1
#  endif
#endif

__device__ __forceinline__ float dot2f(h2 a, h2 b, float c) {
#ifdef HAVE_FDOT2
  return __builtin_amdgcn_fdot2(a, b, c, false);
#else
  return c + (float)a[0] * (float)b[0] + (float)a[1] * (float)b[1];
#endif
}

__device__ __forceinline__ h2 pkh(float a, float b) {
  h2 r; r[0] = (_Float16)a; r[1] = (_Float16)b; return r;
}

__device__ __forceinline__ h2 bch(float x) { return __builtin_bit_cast(h2, x); }
__device__ __forceinline__ float fch(h2 x) { return __builtin_bit_cast(float, x); }

__device__ __forceinline__ float sigmf(float x) { return 1.0f / (1.0f + expf(-x)); }

// LDS-only barrier WITHOUT the vmcnt(0) drain of __syncthreads(). Since r12,
// 6 w1 prefetch loads are in flight at the stage1->2 barrier; __syncthreads'
// vmcnt(0) forces every wave to wait for them BEFORE crossing -- defeating
// the prefetch. LDS handoff only needs lgkmcnt(0) (scratch/global never
// crosses threads). Unlike r11: no sched_barrier(0) pin (that blocked the
// compiler's own interleave), and now there IS a queue to preserve.
__device__ __forceinline__ void bar_lgkm() {
  asm volatile("s_waitcnt lgkmcnt(0)" ::: "memory");
  __builtin_amdgcn_s_barrier();
}

#define DOT4(W, I, Q) \
    a0 = dot2f(W[4*(I)+0], bch(Q.x), a0); \
    a1 = dot2f(W[4*(I)+1], bch(Q.y), a1); \
    a2 = dot2f(W[4*(I)+2], bch(Q.z), a2); \
    a3 = dot2f(W[4*(I)+3], bch(Q.w), a3);

// LDS K-slice padding (h2 elem = 1 dword; bank = dword % 32): slice bases
// offset +4 dwords mod 32 -> K-half runs on disjoint banks (r10: 1.04e8 ->
// 4.4e6 conflict-cycles).
#define PI(i) ((i) + (((i) >> 5) << 2))
#define PA(i) ((i) + (((i) >> 6) << 2))
#define PB(i) ((i) + (((i) >> 5) << 2))

// ---- prep: Wd1 (f32, row-major) -> d_ws as f16, chunk-major interleave.
// ws4[j*512 + t] = f4 of 8 packed halfs = Wd1[row(t)][sub(t)*128 + 8j .. +7].
__global__ void prep_w1(const float* __restrict__ Wd1, f4* __restrict__ ws4) {
  int idx = blockIdx.x * blockDim.x + threadIdx.x;   // 0..8191
  int j  = idx >> 9;
  int tt = idx & 511;
  const float* src = Wd1 + (tt >> 1) * HDIM + (tt & 1) * 128 + j * 8;
  f4 c;
  c.x = fch(pkh(src[0], src[1]));
  c.y = fch(pkh(src[2], src[3]));
  c.z = fch(pkh(src[4], src[5]));
  c.w = fch(pkh(src[6], src[7]));
  ws4[j * 512 + tt] = c;
}

// r16 base (2332us ~ r12's 2317: chain/sync trims null -> latency floor for
// the drain-everything barrier form). This round: lgkm-only barriers at the
// stage1->2 and stage2->3 boundaries so the 6 in-flight w1 prefetch loads
// survive the barrier crossing (T4: never drain vmcnt in the main loop).
__global__ __attribute__((amdgpu_waves_per_eu(2, 2))) __launch_bounds__(512)
void ode_rnn_kernel(const float* __restrict__ ob,   const float* __restrict__ acs,
                    const float* __restrict__ times,
                    const float* __restrict__ We0,  const float* __restrict__ be0,
                    const float* __restrict__ We1,  const float* __restrict__ be1,
                    const float* __restrict__ Wd0,  const float* __restrict__ bd0,
                    const float* __restrict__ bd1,
                    const float* __restrict__ Wd2,  const float* __restrict__ bd2,
                    const float* __restrict__ Wo0,  const float* __restrict__ bo0,
                    const float* __restrict__ Wo1,  const float* __restrict__ bo1,
                    const float* __restrict__ Wih,  const float* __restrict__ Whh,
                    const float* __restrict__ bih,  const float* __restrict__ bn,
                    const f4* __restrict__ ws4,
                    float* __restrict__ out)
{
  const int t    = threadIdx.x;
  const int b    = blockIdx.x;
  const int p    = t >> 1;           // 0..255  H-stage row
  const int sub  = t & 1;            // K-half
  const int r    = t >> 2;           // 0..127  L-stage row
  const int ksub = t & 3;            // K-quarter

  __shared__ __align__(16) float s_lat[LDIM];
  __shared__ __align__(16) float s_gz[LDIM];
  __shared__ __align__(16) float s_gin[LDIM];
  __shared__ __align__(16) float s_ghn[LDIM];
  __shared__ __align__(16) float s_tmp[HDIM];
  __shared__ __align__(16) float s_obs[OBD];
  __shared__ __align__(16) float s_times[NT];
  __shared__ __align__(16) float s_acs[NT * ACD];
  __shared__ __align__(16) h2    s_in16[68];    // 2 x (32 h2 + 4 pad)
  __shared__ __align__(16) h2    s_a16[132];    // 2 x (64 h2 + 4 pad)
  __shared__ __align__(16) h2    s_b16[140];    // 4 x (32 h2 + 4 pad)

  // ---- resident register weights: Wd0 half-row + Wd2 quarter-row ----
  h2 w0[32], w2[32];
  {
    const float2* pp = (const float2*)(Wd0 + p * LDIM + sub * 64);
#pragma unroll
    for (int i = 0; i < 32; ++i) { float2 v = pp[i]; w0[i] = pkh(v.x, v.y); }
  }
  {
    const float2* pp = (const float2*)(Wd2 + r * HDIM + ksub * 64);
#pragma unroll
    for (int i = 0; i < 32; ++i) { float2 v = pp[i]; w2[i] = pkh(v.x, v.y); }
  }
  const f4* wsb = ws4 + t;           // per-thread w1 stream base

  const float bb0 = bd0[p];
  const float bb1 = bd1[p];
  const float bb2 = bd2[r];
  const float rb0 = bo0[p];
  const float gA  = (t < 3 * LDIM) ? bih[t] : 0.0f;
  const float bnr = (t < LDIM) ? bn[t] : 0.0f;

  float latr = 0.0f;                 // lat[r], refreshed in decode()

  // ---- one Dopri5 substep; entry: s_in16 = packed lat, latr = lat[r] ----
  auto substep = [&](float hs) {
    float k0 = 0, k1 = 0, k2 = 0, k3 = 0, k4 = 0;
#pragma unroll
    for (int s = 0; s < 6; ++s) {
      float a0, a1, a2, a3, v;
      // w1 prefetch chunks 0-5: no deps -> issue now; they stay in flight
      // ACROSS the lgkm-only barrier below and land inside stage 2.
      f4 y0 = wsb[0 * 512], y1 = wsb[1 * 512];
      f4 y2 = wsb[2 * 512], y3 = wsb[3 * 512];
      f4 y4 = wsb[4 * 512], y5 = wsb[5 * 512];
      // stage 1: h1 = relu(Wd0 @ z + bd0)
      a0 = a1 = a2 = a3 = 0.0f;
      {
        const f4* src = ((const f4*)s_in16) + sub * 9;
#pragma unroll
        for (int i = 0; i < 8; ++i) { f4 q = src[i]; DOT4(w0, i, q) }
      }
      v = (a0 + a1) + (a2 + a3);
      v += __shfl_xor(v, 1);
      v = fmaxf(v + bb0, 0.0f);
      { float ov = __shfl_xor(v, 2); if ((t & 3) == 0) s_a16[PA(t >> 2)] = pkh(v, ov); }
      bar_lgkm();                    // keep the 6 w1 loads in flight
      // stage 2: h2 = relu(Wd1 @ h1 + bd1) -- streamed weights, 8 accs
      float b0, b1, b2, b3;
      a0 = a1 = a2 = a3 = b0 = b1 = b2 = b3 = 0.0f;
      {
        const f4* act = ((const f4*)s_a16) + sub * 17;
        f4 q;
#define SDA(WV, J) q = act[J]; \
        a0 = dot2f(bch(WV.x), bch(q.x), a0); \
        a1 = dot2f(bch(WV.y), bch(q.y), a1); \
        a2 = dot2f(bch(WV.z), bch(q.z), a2); \
        a3 = dot2f(bch(WV.w), bch(q.w), a3);
#define SDB(WV, J) q = act[J]; \
        b0 = dot2f(bch(WV.x), bch(q.x), b0); \
        b1 = dot2f(bch(WV.y), bch(q.y), b1); \
        b2 = dot2f(bch(WV.z), bch(q.z), b2); \
        b3 = dot2f(bch(WV.w), bch(q.w), b3);
        SDA(y0, 0)  SDB(y1, 1)
        f4 y6 = wsb[6 * 512],  y7 = wsb[7 * 512];
        SDA(y2, 2)  SDB(y3, 3)
        f4 y8 = wsb[8 * 512],  y9 = wsb[9 * 512];
        SDA(y4, 4)  SDB(y5, 5)
        f4 y10 = wsb[10 * 512], y11 = wsb[11 * 512];
        SDA(y6, 6)  SDB(y7, 7)
        f4 y12 = wsb[12 * 512], y13 = wsb[13 * 512];
        SDA(y8, 8)  SDB(y9, 9)
        f4 y14 = wsb[14 * 512], y15 = wsb[15 * 512];
        SDA(y10, 10) SDB(y11, 11)
        SDA(y12, 12) SDB(y13, 13)
        SDA(y14, 14) SDB(y15, 15)
#undef SDA
#undef SDB
      }
      v = ((a0 + a1) + (a2 + a3)) + ((b0 + b1) + (b2 + b3));
      v += __shfl_xor(v, 1);
      v = fmaxf(v + bb1, 0.0f);
      { float ov = __shfl_xor(v, 2); if ((t & 3) == 0) s_b16[PB(t >> 2)] = pkh(v, ov); }
      bar_lgkm();
      // stage 3: k_s = Wd2 @ h2 + bd2, fused RK tail
      a0 = a1 = a2 = a3 = 0.0f;
      {
        const f4* src = ((const f4*)s_b16) + ksub * 9;
#pragma unroll
        for (int i = 0; i < 8; ++i) { f4 q = src[i]; DOT4(w2, i, q) }
      }
      v = (a0 + a1) + (a2 + a3);
      v += __shfl_xor(v, 1);
      v += __shfl_xor(v, 2);
      float kv = v + bb2;              // k_s[r], in every lane of the quad
      float z;
      if (s == 0) {
        k0 = kv; z = latr + hs * (0.2f * kv);
      } else if (s == 1) {
        k1 = kv; z = latr + hs * ((3.0f/40.0f)*k0 + (9.0f/40.0f)*kv);
      } else if (s == 2) {
        k2 = kv; z = latr + hs * ((44.0f/45.0f)*k0 - (56.0f/15.0f)*k1
                                + (32.0f/9.0f)*kv);
      } else if (s == 3) {
        k3 = kv; z = latr + hs * ((19372.0f/6561.0f)*k0 - (25360.0f/2187.0f)*k1
                                + (64448.0f/6561.0f)*k2 - (212.0f/729.0f)*kv);
      } else if (s == 4) {
        k4 = kv; z = latr + hs * ((9017.0f/3168.0f)*k0 - (355.0f/33.0f)*k1
                                + (46732.0f/5247.0f)*k2 + (49.0f/176.0f)*k3
                                - (5103.0f/18656.0f)*kv);
      } else {
        z = latr + hs * ((35.0f/384.0f)*k0 + (500.0f/1113.0f)*k2
                       + (125.0f/192.0f)*k3 - (2187.0f/6784.0f)*k4
                       + (11.0f/84.0f)*kv);
        latr = z;
      }
      { float ov = __shfl_xor(z, 4); if ((t & 7) == 0) s_in16[PI(t >> 3)] = pkh(z, ov); }
      if (s == 5 && ksub == 0) s_lat[r] = z;
      __syncthreads();               // no vm in flight here; full drain ok
    }
  };

  // ---- GRU (fp32; Wih/Whh streamed from L2). Entry: s_lat published by
  // caller (substep trailing barrier / explicit post-encoder barrier) ----
  auto gru = [&](int ts) {
    float vi = gA, vh = 0.0f;
    if (t < 3 * LDIM) {
      const float* xa = s_acs + ts * ACD;
      const f4* wiv = (const f4*)(Wih + t * ACD);
      f4 wa = wiv[0], wb = wiv[1];
      vi += wa.x*xa[0] + wa.y*xa[1] + wa.z*xa[2] + wa.w*xa[3]
          + wb.x*xa[4] + wb.y*xa[5] + wb.z*xa[6] + wb.w*xa[7];
      const f4* wh = (const f4*)(Whh + t * LDIM);
      const f4* xl = (const f4*)s_lat;
#pragma unroll
      for (int k2 = 0; k2 < LDIM / 4; ++k2) {
        f4 w = wh[k2], x = xl[k2];
        vh += w.x*x.x + w.y*x.y + w.z*x.z + w.w*x.w;
      }
    }
    if (t >= LDIM && t < 2 * LDIM)          s_gz[t - LDIM] = vi + vh;
    else if (t >= 2 * LDIM && t < 3 * LDIM) { s_gin[t - 2*LDIM] = vi; s_ghn[t - 2*LDIM] = vh; }
    __syncthreads();
    if (t < LDIM) {
      float rg = sigmf(vi + vh);
      float zg = sigmf(s_gz[t]);
      float ng = tanhf(s_gin[t] + rg * (s_ghn[t] + bnr));
      float y  = (1.0f - zg) * ng + zg * s_lat[t];
      s_lat[t] = y;
      float ov = __shfl_xor(y, 1);
      if (!(t & 1)) s_in16[PI(t >> 1)] = pkh(y, ov);
    }
  };

  // ---- decoder: Wo0/Wo1 streamed f32 from L2; also refreshes latr ----
  auto decode = [&](int ts) {
    __syncthreads();                 // publish s_lat (post-GRU)
    latr = s_lat[r];                 // register copy for the next substeps
    float acc = 0.0f;
    {
      const f4* wr = (const f4*)(Wo0 + p * LDIM + sub * 64);
      const f4* xl = ((const f4*)s_lat) + sub * 16;
#pragma unroll
      for (int k2 = 0; k2 < 16; ++k2) {
        f4 w = wr[k2], x = xl[k2];
        acc += w.x*x.x + w.y*x.y + w.z*x.z + w.w*x.w;
      }
    }
    acc += __shfl_xor(acc, 1);
    acc = fmaxf(acc + rb0, 0.0f);
    { float ov = __shfl_xor(acc, 2); if ((t & 3) == 0) s_a16[PA(t >> 2)] = pkh(acc, ov); }
    __syncthreads();
    // stage B: out row o = t>>4, K-slice sl = t&15 (16 of 256)
    const int o  = t >> 4;
    const int sl = t & 15;
    float v2 = 0.0f;
    {
      const f4* wr = (const f4*)(Wo1 + o * HDIM + sl * 16);
      const h2* xs = s_a16 + sl * 8 + ((sl >> 3) << 2);   // padded slices
#pragma unroll
      for (int i = 0; i < 4; ++i) {
        f4 w = wr[i];
        h2 xa = xs[2*i], xb = xs[2*i+1];
        v2 += w.x*(float)xa[0] + w.y*(float)xa[1]
            + w.z*(float)xb[0] + w.w*(float)xb[1];
      }
    }
    v2 += __shfl_xor(v2, 1);
    v2 += __shfl_xor(v2, 2);
    v2 += __shfl_xor(v2, 4);
    v2 += __shfl_xor(v2, 8);
    if (sl == 0) out[((size_t)b * NT + ts) * OBD + o] = v2 + bo1[o];
    __syncthreads();                 // protect s_a16 before next substep
  };

  // ================= init + encoder =================
  if (t < OBD) s_obs[t] = ob[b * OBD + t];
  if (t < NT)  s_times[t] = times[b * NT + t];
  s_acs[t] = acs[(size_t)b * NT * ACD + t];   // NT*ACD == 512 == blockDim
  __syncthreads();
  if (t < HDIM) {
    float acc = be0[t];
    const float* wr = We0 + t * OBD;
#pragma unroll
    for (int j = 0; j < OBD; ++j) acc += wr[j] * s_obs[j];
    s_tmp[t] = fmaxf(acc, 0.0f);
  }
  __syncthreads();
  {
    const f4* wr = (const f4*)(We1 + r * HDIM + ksub * 64);
    const f4* xs = ((const f4*)s_tmp) + ksub * 16;
    float acc = 0.0f;
#pragma unroll
    for (int k = 0; k < 16; ++k) {
      f4 w = wr[k], x = xs[k];
      acc += w.x*x.x + w.y*x.y + w.z*x.z + w.w*x.w;
    }
    acc += __shfl_xor(acc, 1);
    acc += __shfl_xor(acc, 2);
    if (ksub == 0) s_lat[r] = acc + be1[r];
  }
  __syncthreads();                   // publish encoder s_lat (gru has no entry barrier)

  // ================= time loop =================
  gru(0);
  decode(0);

#pragma unroll 1
  for (int ts = 1; ts < NT; ++ts) {
    float hs = 0.25f * (s_times[ts] - s_times[ts - 1]);
#pragma unroll 1
    for (int su = 0; su < 4; ++su) substep(hs);
    gru(ts);
    decode(ts);
  }
}

extern "C" void kernel_launch(void* const* d_in, const int* in_sizes, int n_in,
                              void* d_out, int out_size, void* d_ws, size_t ws_size,
                              hipStream_t stream) {
  (void)in_sizes; (void)n_in; (void)ws_size; (void)out_size;
  const float* ob    = (const float*)d_in[0];
  const float* acs   = (const float*)d_in[1];
  const float* times = (const float*)d_in[2];
  const float* We0   = (const float*)d_in[3];
  const float* be0   = (const float*)d_in[4];
  const float* We1   = (const float*)d_in[5];
  const float* be1   = (const float*)d_in[6];
  const float* Wd0   = (const float*)d_in[7];
  const float* bd0   = (const float*)d_in[8];
  const float* Wd1   = (const float*)d_in[9];
  const float* bd1   = (const float*)d_in[10];
  const float* Wd2   = (const float*)d_in[11];
  const float* bd2   = (const float*)d_in[12];
  const float* Wo0   = (const float*)d_in[13];
  const float* bo0   = (const float*)d_in[14];
  const float* Wo1   = (const float*)d_in[15];
  const float* bo1   = (const float*)d_in[16];
  const float* Wih   = (const float*)d_in[17];
  const float* Whh   = (const float*)d_in[18];
  const float* bih   = (const float*)d_in[19];
  const float* bn    = (const float*)d_in[20];

  f4* ws4 = (f4*)d_ws;   // 16 chunks x 512 threads x 16 B = 131072 B

  prep_w1<<<dim3(16), dim3(512), 0, stream>>>(Wd1, ws4);
  ode_rnn_kernel<<<dim3(NBATCH), dim3(512), 0, stream>>>(
      ob, acs, times, We0, be0, We1, be1, Wd0, bd0, bd1, Wd2, bd2,
      Wo0, bo0, Wo1, bo1, Wih, Whh, bih, bn, ws4, (float*)d_out);
}

// Round 18
// 2311.229 us; speedup vs baseline: 1.4203x; 1.4203x over previous
//
#include <hip/hip_runtime.h>
#include <stdint.h>

#define NBATCH 128
#define NT     64
#define OBD    32
#define ACD    8
#define LDIM   128
#define HDIM   256

typedef _Float16 h2 __attribute__((ext_vector_type(2)));
typedef float    f4 __attribute__((ext_vector_type(4)));

#if defined(__has_builtin)
#  if __has_builtin(__builtin_amdgcn_fdot2)
#    define HAVE_FDOT2 1
#  endif
#endif

__device__ __forceinline__ float dot2f(h2 a, h2 b, float c) {
#ifdef HAVE_FDOT2
  return __builtin_amdgcn_fdot2(a, b, c, false);
#else
  return c + (float)a[0] * (float)b[0] + (float)a[1] * (float)b[1];
#endif
}

__device__ __forceinline__ h2 pkh(float a, float b) {
  h2 r; r[0] = (_Float16)a; r[1] = (_Float16)b; return r;
}

__device__ __forceinline__ h2 bch(float x) { return __builtin_bit_cast(h2, x); }
__device__ __forceinline__ float fch(h2 x) { return __builtin_bit_cast(float, x); }

__device__ __forceinline__ float sigmf(float x) { return 1.0f / (1.0f + expf(-x)); }

#define DOT4(W, I, Q) \
    a0 = dot2f(W[4*(I)+0], bch(Q.x), a0); \
    a1 = dot2f(W[4*(I)+1], bch(Q.y), a1); \
    a2 = dot2f(W[4*(I)+2], bch(Q.z), a2); \
    a3 = dot2f(W[4*(I)+3], bch(Q.w), a3);

// LDS K-slice padding (h2 elem = 1 dword; bank = dword % 32): slice bases
// offset by +4 dwords mod 32 so K-half runs hit disjoint banks (r10: fixed
// 1.04e8 -> 4.4e6 conflict-cycles).
#define PI(i) ((i) + (((i) >> 5) << 2))
#define PA(i) ((i) + (((i) >> 6) << 2))
#define PB(i) ((i) + (((i) >> 5) << 2))

// ---- prep: Wd1 (f32, row-major) -> d_ws as f16, chunk-major interleave.
// ws4[j*512 + t] = f4 of 8 packed halfs = Wd1[row(t)][sub(t)*128 + 8j .. +7].
// Chunk-major => a wave's load of chunk j is 64 lanes x 16B CONTIGUOUS.
__global__ void prep_w1(const float* __restrict__ Wd1, f4* __restrict__ ws4) {
  int idx = blockIdx.x * blockDim.x + threadIdx.x;   // 0..8191
  int j  = idx >> 9;
  int tt = idx & 511;
  const float* src = Wd1 + (tt >> 1) * HDIM + (tt & 1) * 128 + j * 8;
  f4 c;
  c.x = fch(pkh(src[0], src[1]));
  c.y = fch(pkh(src[2], src[3]));
  c.z = fch(pkh(src[4], src[5]));
  c.w = fch(pkh(src[6], src[7]));
  ws4[j * 512 + tt] = c;
}

// FINAL (r18 = r12 revert, best measured 2317us). 512 threads. H-stages:
// row p=t>>1, K-half sub=t&1. L-stages: row r=t>>2, K-quarter ksub=t&3.
// Wd0/Wd2 resident in VGPRs (128-reg allocator budget); Wd1 streamed f16
// chunk-major from d_ws, hand-pipelined, <=6 f4 in flight; RK state in
// per-lane regs; act slices bank-padded; plain __syncthreads (r11/r17:
// inline-asm barriers defeat the scheduler, +118/+950us).
// 17-round ledger: spills/conflicts/LDS-throughput/chain-depth/occupancy/
// vmcnt all tested -> kernel is block-sync latency-bound (~4536 barrier
// segments x ~500ns, pipes <25% busy); this structure is its floor.
__global__ __attribute__((amdgpu_waves_per_eu(2, 2))) __launch_bounds__(512)
void ode_rnn_kernel(const float* __restrict__ ob,   const float* __restrict__ acs,
                    const float* __restrict__ times,
                    const float* __restrict__ We0,  const float* __restrict__ be0,
                    const float* __restrict__ We1,  const float* __restrict__ be1,
                    const float* __restrict__ Wd0,  const float* __restrict__ bd0,
                    const float* __restrict__ bd1,
                    const float* __restrict__ Wd2,  const float* __restrict__ bd2,
                    const float* __restrict__ Wo0,  const float* __restrict__ bo0,
                    const float* __restrict__ Wo1,  const float* __restrict__ bo1,
                    const float* __restrict__ Wih,  const float* __restrict__ Whh,
                    const float* __restrict__ bih,  const float* __restrict__ bn,
                    const f4* __restrict__ ws4,
                    float* __restrict__ out)
{
  const int t    = threadIdx.x;
  const int b    = blockIdx.x;
  const int p    = t >> 1;           // 0..255  H-stage row
  const int sub  = t & 1;            // K-half
  const int r    = t >> 2;           // 0..127  L-stage row
  const int ksub = t & 3;            // K-quarter

  __shared__ __align__(16) float s_lat[LDIM];
  __shared__ __align__(16) float s_gz[LDIM];
  __shared__ __align__(16) float s_gin[LDIM];
  __shared__ __align__(16) float s_ghn[LDIM];
  __shared__ __align__(16) float s_tmp[HDIM];
  __shared__ __align__(16) float s_obs[OBD];
  __shared__ __align__(16) float s_times[NT];
  __shared__ __align__(16) float s_acs[NT * ACD];
  __shared__ __align__(16) h2    s_in16[68];    // 2 x (32 h2 + 4 pad)
  __shared__ __align__(16) h2    s_a16[132];    // 2 x (64 h2 + 4 pad)
  __shared__ __align__(16) h2    s_b16[140];    // 4 x (32 h2 + 4 pad)

  // ---- resident register weights: Wd0 half-row + Wd2 quarter-row ----
  h2 w0[32], w2[32];
  {
    const float2* pp = (const float2*)(Wd0 + p * LDIM + sub * 64);
#pragma unroll
    for (int i = 0; i < 32; ++i) { float2 v = pp[i]; w0[i] = pkh(v.x, v.y); }
  }
  {
    const float2* pp = (const float2*)(Wd2 + r * HDIM + ksub * 64);
#pragma unroll
    for (int i = 0; i < 32; ++i) { float2 v = pp[i]; w2[i] = pkh(v.x, v.y); }
  }
  const f4* wsb = ws4 + t;           // per-thread w1 stream base

  const float bb0 = bd0[p];
  const float bb1 = bd1[p];
  const float bb2 = bd2[r];
  const float rb0 = bo0[p];
  const float gA  = (t < 3 * LDIM) ? bih[t] : 0.0f;
  const float bnr = (t < LDIM) ? bn[t] : 0.0f;

  float latr = 0.0f;                 // lat[r], refreshed in decode()

  // ---- one Dopri5 substep; entry: s_in16 = packed lat, latr = lat[r] ----
  auto substep = [&](float hs) {
    float k0 = 0, k1 = 0, k2 = 0, k3 = 0, k4 = 0;
#pragma unroll
    for (int s = 0; s < 6; ++s) {
      float a0, a1, a2, a3, v;
      // w1 prefetch chunks 0-3: no deps -> issue now, land by stage 2
      f4 y0 = wsb[0 * 512], y1 = wsb[1 * 512];
      f4 y2 = wsb[2 * 512], y3 = wsb[3 * 512];
      // stage 1: h1 = relu(Wd0 @ z + bd0)
      a0 = a1 = a2 = a3 = 0.0f;
      {
        const f4* src = ((const f4*)s_in16) + sub * 9;
#pragma unroll
        for (int i = 0; i < 8; ++i) { f4 q = src[i]; DOT4(w0, i, q) }
      }
      v = (a0 + a1) + (a2 + a3);
      v += __shfl_xor(v, 1);
      v = fmaxf(v + bb0, 0.0f);
      { float ov = __shfl_xor(v, 2); if ((t & 3) == 0) s_a16[PA(t >> 2)] = pkh(v, ov); }
      __syncthreads();
      // stage 2: h2 = relu(Wd1 @ h1 + bd1) -- streamed, hand-pipelined
      a0 = a1 = a2 = a3 = 0.0f;
      {
        const f4* act = ((const f4*)s_a16) + sub * 17;
        f4 q;
#define SDOT(WV, J) q = act[J]; \
        a0 = dot2f(bch(WV.x), bch(q.x), a0); \
        a1 = dot2f(bch(WV.y), bch(q.y), a1); \
        a2 = dot2f(bch(WV.z), bch(q.z), a2); \
        a3 = dot2f(bch(WV.w), bch(q.w), a3);
        f4 y4 = wsb[4 * 512],  y5 = wsb[5 * 512];
        SDOT(y0, 0)  SDOT(y1, 1)
        f4 y6 = wsb[6 * 512],  y7 = wsb[7 * 512];
        SDOT(y2, 2)  SDOT(y3, 3)
        f4 y8 = wsb[8 * 512],  y9 = wsb[9 * 512];
        SDOT(y4, 4)  SDOT(y5, 5)
        f4 y10 = wsb[10 * 512], y11 = wsb[11 * 512];
        SDOT(y6, 6)  SDOT(y7, 7)
        f4 y12 = wsb[12 * 512], y13 = wsb[13 * 512];
        SDOT(y8, 8)  SDOT(y9, 9)
        f4 y14 = wsb[14 * 512], y15 = wsb[15 * 512];
        SDOT(y10, 10) SDOT(y11, 11)
        SDOT(y12, 12) SDOT(y13, 13)
        SDOT(y14, 14) SDOT(y15, 15)
#undef SDOT
      }
      v = (a0 + a1) + (a2 + a3);
      v += __shfl_xor(v, 1);
      v = fmaxf(v + bb1, 0.0f);
      { float ov = __shfl_xor(v, 2); if ((t & 3) == 0) s_b16[PB(t >> 2)] = pkh(v, ov); }
      __syncthreads();
      // stage 3: k_s = Wd2 @ h2 + bd2, fused RK tail
      a0 = a1 = a2 = a3 = 0.0f;
      {
        const f4* src = ((const f4*)s_b16) + ksub * 9;
#pragma unroll
        for (int i = 0; i < 8; ++i) { f4 q = src[i]; DOT4(w2, i, q) }
      }
      v = (a0 + a1) + (a2 + a3);
      v += __shfl_xor(v, 1);
      v += __shfl_xor(v, 2);
      float kv = v + bb2;              // k_s[r], in every lane of the quad
      float z;
      if (s == 0) {
        k0 = kv; z = latr + hs * (0.2f * kv);
      } else if (s == 1) {
        k1 = kv; z = latr + hs * ((3.0f/40.0f)*k0 + (9.0f/40.0f)*kv);
      } else if (s == 2) {
        k2 = kv; z = latr + hs * ((44.0f/45.0f)*k0 - (56.0f/15.0f)*k1
                                + (32.0f/9.0f)*kv);
      } else if (s == 3) {
        k3 = kv; z = latr + hs * ((19372.0f/6561.0f)*k0 - (25360.0f/2187.0f)*k1
                                + (64448.0f/6561.0f)*k2 - (212.0f/729.0f)*kv);
      } else if (s == 4) {
        k4 = kv; z = latr + hs * ((9017.0f/3168.0f)*k0 - (355.0f/33.0f)*k1
                                + (46732.0f/5247.0f)*k2 + (49.0f/176.0f)*k3
                                - (5103.0f/18656.0f)*kv);
      } else {
        z = latr + hs * ((35.0f/384.0f)*k0 + (500.0f/1113.0f)*k2
                       + (125.0f/192.0f)*k3 - (2187.0f/6784.0f)*k4
                       + (11.0f/84.0f)*kv);
        latr = z;
      }
      { float ov = __shfl_xor(z, 4); if ((t & 7) == 0) s_in16[PI(t >> 3)] = pkh(z, ov); }
      if (s == 5 && ksub == 0) s_lat[r] = z;
      __syncthreads();
    }
  };

  // ---- GRU (fp32; Wih/Whh streamed from L2) ----
  auto gru = [&](int ts) {
    __syncthreads();                 // publish s_lat
    float vi = gA, vh = 0.0f;
    if (t < 3 * LDIM) {
      const float* xa = s_acs + ts * ACD;
      const f4* wiv = (const f4*)(Wih + t * ACD);
      f4 wa = wiv[0], wb = wiv[1];
      vi += wa.x*xa[0] + wa.y*xa[1] + wa.z*xa[2] + wa.w*xa[3]
          + wb.x*xa[4] + wb.y*xa[5] + wb.z*xa[6] + wb.w*xa[7];
      const f4* wh = (const f4*)(Whh + t * LDIM);
      const f4* xl = (const f4*)s_lat;
#pragma unroll
      for (int k2 = 0; k2 < LDIM / 4; ++k2) {
        f4 w = wh[k2], x = xl[k2];
        vh += w.x*x.x + w.y*x.y + w.z*x.z + w.w*x.w;
      }
    }
    if (t >= LDIM && t < 2 * LDIM)          s_gz[t - LDIM] = vi + vh;
    else if (t >= 2 * LDIM && t < 3 * LDIM) { s_gin[t - 2*LDIM] = vi; s_ghn[t - 2*LDIM] = vh; }
    __syncthreads();
    if (t < LDIM) {
      float rg = sigmf(vi + vh);
      float zg = sigmf(s_gz[t]);
      float ng = tanhf(s_gin[t] + rg * (s_ghn[t] + bnr));
      float y  = (1.0f - zg) * ng + zg * s_lat[t];
      s_lat[t] = y;
      float ov = __shfl_xor(y, 1);
      if (!(t & 1)) s_in16[PI(t >> 1)] = pkh(y, ov);
    }
  };

  // ---- decoder: Wo0/Wo1 streamed f32 from L2; also refreshes latr ----
  auto decode = [&](int ts) {
    __syncthreads();                 // publish s_lat (post-GRU)
    latr = s_lat[r];                 // register copy for the next substeps
    float acc = 0.0f;
    {
      const f4* wr = (const f4*)(Wo0 + p * LDIM + sub * 64);
      const f4* xl = ((const f4*)s_lat) + sub * 16;
#pragma unroll
      for (int k2 = 0; k2 < 16; ++k2) {
        f4 w = wr[k2], x = xl[k2];
        acc += w.x*x.x + w.y*x.y + w.z*x.z + w.w*x.w;
      }
    }
    acc += __shfl_xor(acc, 1);
    acc = fmaxf(acc + rb0, 0.0f);
    { float ov = __shfl_xor(acc, 2); if ((t & 3) == 0) s_a16[PA(t >> 2)] = pkh(acc, ov); }
    __syncthreads();
    // stage B: out row o = t>>4, K-slice sl = t&15 (16 of 256)
    const int o  = t >> 4;
    const int sl = t & 15;
    float v2 = 0.0f;
    {
      const f4* wr = (const f4*)(Wo1 + o * HDIM + sl * 16);
      const h2* xs = s_a16 + sl * 8 + ((sl >> 3) << 2);   // padded slices
#pragma unroll
      for (int i = 0; i < 4; ++i) {
        f4 w = wr[i];
        h2 xa = xs[2*i], xb = xs[2*i+1];
        v2 += w.x*(float)xa[0] + w.y*(float)xa[1]
            + w.z*(float)xb[0] + w.w*(float)xb[1];
      }
    }
    v2 += __shfl_xor(v2, 1);
    v2 += __shfl_xor(v2, 2);
    v2 += __shfl_xor(v2, 4);
    v2 += __shfl_xor(v2, 8);
    if (sl == 0) out[((size_t)b * NT + ts) * OBD + o] = v2 + bo1[o];
    __syncthreads();                 // protect s_a16 before next substep
  };

  // ================= init + encoder =================
  if (t < OBD) s_obs[t] = ob[b * OBD + t];
  if (t < NT)  s_times[t] = times[b * NT + t];
  s_acs[t] = acs[(size_t)b * NT * ACD + t];   // NT*ACD == 512 == blockDim
  __syncthreads();
  if (t < HDIM) {
    float acc = be0[t];
    const float* wr = We0 + t * OBD;
#pragma unroll
    for (int j = 0; j < OBD; ++j) acc += wr[j] * s_obs[j];
    s_tmp[t] = fmaxf(acc, 0.0f);
  }
  __syncthreads();
  {
    const f4* wr = (const f4*)(We1 + r * HDIM + ksub * 64);
    const f4* xs = ((const f4*)s_tmp) + ksub * 16;
    float acc = 0.0f;
#pragma unroll
    for (int k = 0; k < 16; ++k) {
      f4 w = wr[k], x = xs[k];
      acc += w.x*x.x + w.y*x.y + w.z*x.z + w.w*x.w;
    }
    acc += __shfl_xor(acc, 1);
    acc += __shfl_xor(acc, 2);
    if (ksub == 0) s_lat[r] = acc + be1[r];
  }

  // ================= time loop =================
  gru(0);
  decode(0);

#pragma unroll 1
  for (int ts = 1; ts < NT; ++ts) {
    float hs = 0.25f * (s_times[ts] - s_times[ts - 1]);
#pragma unroll 1
    for (int su = 0; su < 4; ++su) substep(hs);
    gru(ts);
    decode(ts);
  }
}

extern "C" void kernel_launch(void* const* d_in, const int* in_sizes, int n_in,
                              void* d_out, int out_size, void* d_ws, size_t ws_size,
                              hipStream_t stream) {
  (void)in_sizes; (void)n_in; (void)ws_size; (void)out_size;
  const float* ob    = (const float*)d_in[0];
  const float* acs   = (const float*)d_in[1];
  const float* times = (const float*)d_in[2];
  const float* We0   = (const float*)d_in[3];
  const float* be0   = (const float*)d_in[4];
  const float* We1   = (const float*)d_in[5];
  const float* be1   = (const float*)d_in[6];
  const float* Wd0   = (const float*)d_in[7];
  const float* bd0   = (const float*)d_in[8];
  const float* Wd1   = (const float*)d_in[9];
  const float* bd1   = (const float*)d_in[10];
  const float* Wd2   = (const float*)d_in[11];
  const float* bd2   = (const float*)d_in[12];
  const float* Wo0   = (const float*)d_in[13];
  const float* bo0   = (const float*)d_in[14];
  const float* Wo1   = (const float*)d_in[15];
  const float* bo1   = (const float*)d_in[16];
  const float* Wih   = (const float*)d_in[17];
  const float* Whh   = (const float*)d_in[18];
  const float* bih   = (const float*)d_in[19];
  const float* bn    = (const float*)d_in[20];

  f4* ws4 = (f4*)d_ws;   // 16 chunks x 512 threads x 16 B = 131072 B

  prep_w1<<<dim3(16), dim3(512), 0, stream>>>(Wd1, ws4);
  ode_rnn_kernel<<<dim3(NBATCH), dim3(512), 0, stream>>>(
      ob, acs, times, We0, be0, We1, be1, Wd0, bd0, bd1, Wd2, bd2,
      Wo0, bo0, Wo1, bo1, Wih, Whh, bih, bn, ws4, (float*)d_out);
}